// Round 7
// baseline (749.014 us; speedup 1.0000x reference)
//
#include <hip/hip_runtime.h>

#define NN 50000
#define NE 800000
#define DD 64
#define NL 5
#define NG 256
#define NC 10
#define BN_EPS 1e-5f
#define NCHUNK ((NN + 255) / 256)   // 196
#define GROWS 128                    // rows per gemm block
#define GT (GROWS / 16)              // 16-row tiles per block
#define SAW 68                       // staged-A row stride (uints): 2-way conflicts only

typedef __attribute__((ext_vector_type(8))) short bf16x8;
typedef __attribute__((ext_vector_type(4))) float f32x4;

// Pack two floats as bf16 (RNE) into one uint: low16 = q, high16 = v.
__device__ inline unsigned int pack_bf16x2(float q, float v) {
    unsigned int uq = __float_as_uint(q);
    unsigned int uv = __float_as_uint(v);
    uq += 0x7FFFu + ((uq >> 16) & 1u);
    uv += 0x7FFFu + ((uv >> 16) & 1u);
    return (uv & 0xFFFF0000u) | (uq >> 16);
}

__device__ inline float sigmoidf_fast(float x) {
    return 1.f / (1.f + __expf(-x));
}

// Split fp32 into bf16 hi (RTZ) + bf16 lo (residual). hi+lo ~ x to ~2^-17.
__device__ inline void split_bf16(float x, short& h, short& l) {
    const unsigned u  = __float_as_uint(x);
    const unsigned hb = u & 0xFFFF0000u;
    h = (short)(hb >> 16);
    const float lo = x - __uint_as_float(hb);
    l = (short)(__float_as_uint(lo) >> 16);
}

// gate-fma for one packed bf16 q|v edge value
__device__ inline float gate_fma(float k, unsigned p, float acc) {
    const float q = __uint_as_float(p << 16);
    const float v = __uint_as_float(p & 0xFFFF0000u);
    return fmaf(sigmoidf_fast(k + q), v, acc);
}

// ---------------------------------------------------------------------------
// MFMA gemm4 (unchanged from R6): K/Q/V/S = BN(Hin) @ W* + b*. Split-bf16,
// 3 MFMAs per 16x16x32 product, fp32 accumulate. BN of previous layer folded.
// A-tile staged once per block in LDS as packed split-bf16.
// ---------------------------------------------------------------------------
__global__ __launch_bounds__(256) void gemm4_mfma(
    const float* __restrict__ Hin,
    const float* __restrict__ Wk, const float* __restrict__ Wq,
    const float* __restrict__ Wv, const float* __restrict__ Ws,
    const float* __restrict__ bk, const float* __restrict__ bq,
    const float* __restrict__ bv, const float* __restrict__ bs,
    const float* __restrict__ prevStats,   // null for layer 0
    const float* __restrict__ prevGamma, const float* __restrict__ prevBeta,
    float* __restrict__ K, unsigned int* __restrict__ QVp,
    float* __restrict__ OUT)
{
    __shared__ unsigned int sA[GROWS * SAW];   // 34 KB packed split-bf16 A
    __shared__ float sAB[128];                 // a[64], b[64]
    const int tid = threadIdx.x;

    if (tid < 64) {
        float a = 1.f, b = 0.f;
        if (prevStats) {
            const float invN = 1.0f / (float)NN;
            const float mean = prevStats[tid] * invN;
            const float var  = prevStats[64 + tid] * invN - mean * mean;
            const float inv  = rsqrtf(var + BN_EPS);
            a = inv * prevGamma[tid];
            b = prevBeta[tid] - mean * a;
        }
        sAB[tid]      = a;
        sAB[64 + tid] = b;
    }
    __syncthreads();

    const int row0 = blockIdx.x * GROWS;
    for (int i = tid; i < GROWS * 16; i += 256) {
        const int row = i >> 4;
        const int k4  = (i & 15) * 4;
        float4 x = make_float4(0.f, 0.f, 0.f, 0.f);
        if (row0 + row < NN)
            x = *(const float4*)(Hin + (size_t)(row0 + row) * DD + k4);
        const float xs[4] = {x.x, x.y, x.z, x.w};
        unsigned int* dst = &sA[row * SAW + k4];
#pragma unroll
        for (int j = 0; j < 4; j++) {
            const float xv = fmaf(xs[j], sAB[k4 + j], sAB[64 + k4 + j]);
            short hs, ls;
            split_bf16(xv, hs, ls);
            dst[j] = ((unsigned int)(unsigned short)hs << 16) | (unsigned short)ls;
        }
    }

    const int wave = tid >> 6;    // column tile 0..3
    const int lane = tid & 63;
    const int n15  = lane & 15;
    const int g    = lane >> 4;   // quad
    const int col  = wave * 16 + n15;

    const float* Wm[4] = {Wk, Wq, Wv, Ws};
    bf16x8 wh[4][2], wl[4][2];
#pragma unroll
    for (int m = 0; m < 4; m++) {
#pragma unroll
        for (int c = 0; c < 2; c++) {
            bf16x8 h, l;
#pragma unroll
            for (int j = 0; j < 8; j++) {
                const int k = g * 8 + j + 32 * c;
                short hs, ls;
                split_bf16(Wm[m][k * DD + col], hs, ls);
                h[j] = hs; l[j] = ls;
            }
            wh[m][c] = h; wl[m][c] = l;
        }
    }

    const float bkc = bk[col], bqc = bq[col], bvc = bv[col], bsc = bs[col];
    __syncthreads();

#pragma unroll 1
    for (int t = 0; t < GT; t++) {
        const int rowbase = row0 + t * 16;
        if (rowbase >= NN) break;   // NN % 16 == 0

        bf16x8 ah[2], al[2];
#pragma unroll
        for (int c = 0; c < 2; c++) {
            const uint4 u0 = *(const uint4*)&sA[(t * 16 + n15) * SAW + g * 8 + 32 * c];
            const uint4 u1 = *(const uint4*)&sA[(t * 16 + n15) * SAW + g * 8 + 32 * c + 4];
            const unsigned int us[8] = {u0.x, u0.y, u0.z, u0.w, u1.x, u1.y, u1.z, u1.w};
            bf16x8 h, l;
#pragma unroll
            for (int j = 0; j < 8; j++) {
                h[j] = (short)(us[j] >> 16);
                l[j] = (short)(us[j] & 0xFFFFu);
            }
            ah[c] = h; al[c] = l;
        }

        f32x4 acc[4];
#pragma unroll
        for (int m = 0; m < 4; m++) acc[m] = (f32x4){0.f, 0.f, 0.f, 0.f};

#pragma unroll
        for (int c = 0; c < 2; c++) {
#pragma unroll
            for (int m = 0; m < 4; m++) {
                acc[m] = __builtin_amdgcn_mfma_f32_16x16x32_bf16(ah[c], wh[m][c], acc[m], 0, 0, 0);
                acc[m] = __builtin_amdgcn_mfma_f32_16x16x32_bf16(al[c], wh[m][c], acc[m], 0, 0, 0);
                acc[m] = __builtin_amdgcn_mfma_f32_16x16x32_bf16(ah[c], wl[m][c], acc[m], 0, 0, 0);
            }
        }

#pragma unroll
        for (int r = 0; r < 4; r++) {
            const int row = rowbase + g * 4 + r;
            const size_t o = (size_t)row * DD + col;
            K[o]   = acc[0][r] + bkc;
            QVp[o] = pack_bf16x2(acc[1][r] + bqc, acc[2][r] + bvc);
            OUT[o] = acc[3][r] + bsc;
        }
    }
}

// ---------------------------------------------------------------------------
// CSR build: histogram of dst, two-level exclusive scan, scatter fill.
// ---------------------------------------------------------------------------
__global__ __launch_bounds__(256) void deg_kernel(
    const int* __restrict__ ei, int* __restrict__ deg)
{
    const int e = blockIdx.x * 256 + threadIdx.x;
    if (e < NE) atomicAdd(&deg[ei[NE + e]], 1);
}

__global__ __launch_bounds__(256) void scan_partial_kernel(
    const int* __restrict__ deg, int* __restrict__ psums)
{
    __shared__ int ls[256];
    const int i = blockIdx.x * 256 + threadIdx.x;
    ls[threadIdx.x] = (i < NN) ? deg[i] : 0;
    __syncthreads();
    for (int off = 128; off > 0; off >>= 1) {
        if (threadIdx.x < off) ls[threadIdx.x] += ls[threadIdx.x + off];
        __syncthreads();
    }
    if (threadIdx.x == 0) psums[blockIdx.x] = ls[0];
}

__global__ void scan_offsets_kernel(int* __restrict__ psums, int* __restrict__ rowst)
{
    if (threadIdx.x == 0) {
        int running = 0;
        for (int i = 0; i < NCHUNK; i++) {
            int t = psums[i];
            psums[i] = running;
            running += t;
        }
        rowst[NN] = running;  // == NE
    }
}

__global__ __launch_bounds__(256) void scan_final_kernel(
    const int* __restrict__ deg, const int* __restrict__ psums,
    int* __restrict__ rowst, int* __restrict__ cursor)
{
    __shared__ int ls[256];
    const int i = blockIdx.x * 256 + threadIdx.x;
    const int x = (i < NN) ? deg[i] : 0;
    ls[threadIdx.x] = x;
    __syncthreads();
    for (int off = 1; off < 256; off <<= 1) {
        int v = (threadIdx.x >= off) ? ls[threadIdx.x - off] : 0;
        __syncthreads();
        ls[threadIdx.x] += v;
        __syncthreads();
    }
    if (i < NN) {
        const int excl = psums[blockIdx.x] + ls[threadIdx.x] - x;
        rowst[i]  = excl;
        cursor[i] = excl;
    }
}

__global__ __launch_bounds__(256) void fill_kernel(
    const int* __restrict__ ei, int* __restrict__ cursor, int* __restrict__ csr)
{
    const int e = blockIdx.x * 256 + threadIdx.x;
    if (e < NE) {
        const int src = ei[e];
        const int dst = ei[NE + e];
        csr[atomicAdd(&cursor[dst], 1)] = src;
    }
}

// ---------------------------------------------------------------------------
// Gather v3: one wave per dst node; each lane owns TWO columns (uint2 =
// 8 B/lane), so a HALF-wave covers one QVp row and one load instruction
// fetches two edges' rows. Half 0 takes even CSR slots, half 1 odd; halves
// combine via shfl_xor(32). Unroll-4 per half = 8 edges in flight.
// H = relu(H_skip + acc) in place + fused BN stats.
// ---------------------------------------------------------------------------
#define GATHER_BLOCKS 2048
__global__ __launch_bounds__(256) void gather_kernel(
    const int* __restrict__ rowst, const int* __restrict__ csr,
    const float* __restrict__ K, const unsigned int* __restrict__ QVp,
    float* H, float* __restrict__ stats)
{
    const int tid  = threadIdx.x;
    const int wv   = tid >> 6;
    const int lane = tid & 63;
    const int half = lane >> 5;
    const int m    = lane & 31;       // column pair: cols 2m, 2m+1
    const uint2* QVp2 = (const uint2*)QVp;

    float s0 = 0.f, s20 = 0.f, s1 = 0.f, s21 = 0.f;

    for (int n = blockIdx.x * 4 + wv; n < NN; n += GATHER_BLOCKS * 4) {
        const float2 k2 = *(const float2*)(K + (size_t)n * DD + 2 * m);
        const int e0 = rowst[n], e1 = rowst[n + 1];
        float a0 = 0.f, a1 = 0.f;
        int i = e0 + half;
        // main loop: 4 edges per half per iteration (8 edges per wave)
        while (i + 6 < e1) {
            const int c0 = csr[i], c1 = csr[i + 2], c2 = csr[i + 4], c3 = csr[i + 6];
            const uint2 p0 = QVp2[(size_t)c0 * 32 + m];
            const uint2 p1 = QVp2[(size_t)c1 * 32 + m];
            const uint2 p2 = QVp2[(size_t)c2 * 32 + m];
            const uint2 p3 = QVp2[(size_t)c3 * 32 + m];
            a0 = gate_fma(k2.x, p0.x, a0); a1 = gate_fma(k2.y, p0.y, a1);
            a0 = gate_fma(k2.x, p1.x, a0); a1 = gate_fma(k2.y, p1.y, a1);
            a0 = gate_fma(k2.x, p2.x, a0); a1 = gate_fma(k2.y, p2.y, a1);
            a0 = gate_fma(k2.x, p3.x, a0); a1 = gate_fma(k2.y, p3.y, a1);
            i += 8;
        }
        // tail: remaining edges for this half (stride 2)
        while (i < e1) {
            const uint2 p0 = QVp2[(size_t)csr[i] * 32 + m];
            a0 = gate_fma(k2.x, p0.x, a0);
            a1 = gate_fma(k2.y, p0.y, a1);
            i += 2;
        }
        // combine halves
        a0 += __shfl_xor(a0, 32);
        a1 += __shfl_xor(a1, 32);
        if (half == 0) {
            const float2 h2 = *(const float2*)(H + (size_t)n * DD + 2 * m);
            const float o0 = fmaxf(h2.x + a0, 0.f);
            const float o1 = fmaxf(h2.y + a1, 0.f);
            *(float2*)(H + (size_t)n * DD + 2 * m) = make_float2(o0, o1);
            s0 += o0; s20 += o0 * o0;
            s1 += o1; s21 += o1 * o1;
        }
    }

    __shared__ float ls[4][64], ls2[4][64];
    if (half == 0) {
        ls[wv][2 * m]      = s0;  ls2[wv][2 * m]      = s20;
        ls[wv][2 * m + 1]  = s1;  ls2[wv][2 * m + 1]  = s21;
    }
    __syncthreads();
    if (tid < 64) {
        const float a = ls[0][tid] + ls[1][tid] + ls[2][tid] + ls[3][tid];
        const float b = ls2[0][tid] + ls2[1][tid] + ls2[2][tid] + ls2[3][tid];
        atomicAdd(&stats[tid], a);
        atomicAdd(&stats[64 + tid], b);
    }
}

// ---------------------------------------------------------------------------
// Pooled segment-sum (batch sorted -> run-length accumulate, flush on change).
// ---------------------------------------------------------------------------
#define POOL_ROWS 196
__global__ __launch_bounds__(64) void pool_kernel(
    const float* __restrict__ H, const int* __restrict__ batch,
    float* __restrict__ psum, float* __restrict__ pcnt)
{
    const int c  = threadIdx.x;
    const int r0 = blockIdx.x * POOL_ROWS;
    if (r0 >= NN) return;
    const int r1 = min(r0 + POOL_ROWS, NN);

    int cur = batch[r0];
    float acc = 0.f, cnt = 0.f;
    for (int r = r0; r < r1; r++) {
        const int g = batch[r];
        if (g != cur) {
            atomicAdd(&psum[cur * DD + c], acc);
            if (c == 0) atomicAdd(&pcnt[cur], cnt);
            acc = 0.f; cnt = 0.f; cur = g;
        }
        acc += H[(size_t)r * DD + c];
        cnt += 1.f;
    }
    atomicAdd(&psum[cur * DD + c], acc);
    if (c == 0) atomicAdd(&pcnt[cur], cnt);
}

// ---------------------------------------------------------------------------
// Final: pooled mean -> (folded last-layer BN affine) -> logits -> softmax.
// ---------------------------------------------------------------------------
__global__ __launch_bounds__(256) void final_kernel(
    const float* __restrict__ psum, const float* __restrict__ pcnt,
    const float* __restrict__ stats,
    const float* __restrict__ gamma, const float* __restrict__ beta,
    const float* __restrict__ Wlin, const float* __restrict__ blin,
    float* __restrict__ out)
{
    const int g = blockIdx.x * blockDim.x + threadIdx.x;
    if (g >= NG) return;

    const float invc = 1.0f / fmaxf(pcnt[g], 1.0f);
    const float invN = 1.0f / (float)NN;
    float p[DD];
#pragma unroll
    for (int d = 0; d < DD; d++) {
        const float mean = stats[d] * invN;
        const float var  = stats[64 + d] * invN - mean * mean;
        const float inv  = rsqrtf(var + BN_EPS);
        const float a = inv * gamma[d];
        const float b = beta[d] - mean * a;
        p[d] = fmaf(psum[g * DD + d] * invc, a, b);
    }

    float logits[NC];
    float m = -1e30f;
#pragma unroll
    for (int c = 0; c < NC; c++) {
        float acc = blin[c];
#pragma unroll
        for (int d = 0; d < DD; d++) acc = fmaf(p[d], Wlin[d * NC + c], acc);
        logits[c] = acc;
        m = fmaxf(m, acc);
    }
    float sum = 0.f;
#pragma unroll
    for (int c = 0; c < NC; c++) {
        logits[c] = __expf(logits[c] - m);
        sum += logits[c];
    }
    const float inv = 1.f / sum;
#pragma unroll
    for (int c = 0; c < NC; c++) out[g * NC + c] = logits[c] * inv;
}

// ---------------------------------------------------------------------------
extern "C" void kernel_launch(void* const* d_in, const int* in_sizes, int n_in,
                              void* d_out, int out_size, void* d_ws, size_t ws_size,
                              hipStream_t stream)
{
    const float* X     = (const float*)d_in[0];
    const int*   ei    = (const int*)d_in[1];
    const int*   batch = (const int*)d_in[2];
    const float* Wk    = (const float*)d_in[3];
    const float* Wq    = (const float*)d_in[4];
    const float* Wv    = (const float*)d_in[5];
    const float* Ws    = (const float*)d_in[6];
    const float* bk    = (const float*)d_in[7];
    const float* bq    = (const float*)d_in[8];
    const float* bv    = (const float*)d_in[9];
    const float* bconv = (const float*)d_in[10];
    const float* gamma = (const float*)d_in[11];
    const float* beta  = (const float*)d_in[12];
    const float* Wlin  = (const float*)d_in[13];
    const float* blin  = (const float*)d_in[14];
    float* out = (float*)d_out;

    float* ws = (float*)d_ws;
    const size_t M = (size_t)NN * DD;
    float*        K     = ws;                       // M
    unsigned int* QVp   = (unsigned int*)(K + M);   // M (packed bf16 q|v)
    float*        H0    = (float*)(QVp + M);        // M
    float*        H1    = H0 + M;                   // M (gemm ping-pong)
    // --- contiguous zero-init region ---
    int*   deg   = (int*)(H1 + M);                  // NN
    float* psum  = (float*)(deg + NN);              // NG*DD
    float* pcnt  = psum + (size_t)NG * DD;          // NG
    float* stats = pcnt + NG;                       // NL*128
    // --- end zero region ---
    int* rowst  = (int*)(stats + NL * 128);         // NN+1
    int* cursor = rowst + NN + 1;                   // NN
    int* psums  = cursor + NN;                      // 256
    int* csr    = psums + 256;                      // NE

    const size_t zero_bytes = (size_t)(NN + NG * DD + NG + NL * 128) * sizeof(float);
    hipMemsetAsync(deg, 0, zero_bytes, stream);

    // ---- CSR build ----
    deg_kernel<<<(NE + 255) / 256, 256, 0, stream>>>(ei, deg);
    scan_partial_kernel<<<NCHUNK, 256, 0, stream>>>(deg, psums);
    scan_offsets_kernel<<<1, 64, 0, stream>>>(psums, rowst);
    scan_final_kernel<<<NCHUNK, 256, 0, stream>>>(deg, psums, rowst, cursor);
    fill_kernel<<<(NE + 255) / 256, 256, 0, stream>>>(ei, cursor, csr);

    // ---- layers (BN folded into next GEMM / final) ----
    const float* hin = X;
    for (int l = 0; l < NL; l++) {
        float* hout = (l & 1) ? H1 : H0;
        const float* pS = l ? stats + (l - 1) * 128 : nullptr;
        const float* pG = l ? gamma + (l - 1) * 64  : nullptr;
        const float* pB = l ? beta  + (l - 1) * 64  : nullptr;
        gemm4_mfma<<<(NN + GROWS - 1) / GROWS, 256, 0, stream>>>(
            hin, Wk + l * 4096, Wq + l * 4096, Wv + l * 4096, Ws + l * 4096,
            bk + l * 64, bq + l * 64, bv + l * 64, bconv + l * 64,
            pS, pG, pB, K, QVp, hout);
        gather_kernel<<<GATHER_BLOCKS, 256, 0, stream>>>(
            rowst, csr, K, QVp, hout, stats + l * 128);
        hin = hout;
    }

    pool_kernel<<<(NN + POOL_ROWS - 1) / POOL_ROWS, 64, 0, stream>>>(hin, batch, psum, pcnt);
    final_kernel<<<1, 256, 0, stream>>>(
        psum, pcnt, stats + 4 * 128, gamma + 4 * 64, beta + 4 * 64, Wlin, blin, out);
}